// Round 4
// baseline (1224.167 us; speedup 1.0000x reference)
//
#include <hip/hip_runtime.h>
#include <stdint.h>

#define T_TOK 8192
#define H_DIM 1024
#define E_NUM 8
#define F_DIM 2048
#define BATCH 4
#define AUX_COEF 0.001f
#define Z_COEF 0.001f

#define NBLK_TOK 32       // blocks for hist/scatter (8192/256)

// ---- big-tile grouped GEMM params ----
#define GBM 256
#define GBN 256
#define GBK 64
#define MT_CAP 16         // 16*256 = 4096 rows capacity per expert (counts ~2048±55)

typedef __bf16 bf16x8 __attribute__((ext_vector_type(8)));
typedef float f32x4 __attribute__((ext_vector_type(4)));

__device__ __forceinline__ unsigned short f2bf(float f) {
    union { float f; uint32_t u; } v; v.f = f;
    uint32_t u = v.u;
    return (unsigned short)((u + 0x7FFFu + ((u >> 16) & 1u)) >> 16);
}
__device__ __forceinline__ float bf2f(unsigned short u) {
    union { uint32_t u; float f; } v; v.u = ((uint32_t)u) << 16; return v.f;
}

// async global->LDS, 16 B per lane; LDS dest = wave-uniform base + lane*16
__device__ __forceinline__ void gl_lds16(const void* g, void* l) {
    __builtin_amdgcn_global_load_lds((const __attribute__((address_space(1))) uint32_t*)g,
                                     (__attribute__((address_space(3))) uint32_t*)l, 16, 0, 0);
}

// ------------- transpose+convert: in [E,R,C] fp32 -> out [E,C,R] bf16 -------------
__global__ void transpose_conv_kernel(const float* __restrict__ in, unsigned short* __restrict__ out,
                                      int R, int C) {
    __shared__ float tile[32][33];
    int e = blockIdx.z;
    const float* ine = in + (size_t)e * R * C;
    unsigned short* oute = out + (size_t)e * R * C;
    int tx = threadIdx.x & 31, ty = threadIdx.x >> 5;  // 32x8
    int c0 = blockIdx.x * 32, r0 = blockIdx.y * 32;
#pragma unroll
    for (int i = 0; i < 4; i++) {
        int r = r0 + ty + i * 8;
        tile[ty + i * 8][tx] = ine[(size_t)r * C + c0 + tx];
    }
    __syncthreads();
#pragma unroll
    for (int i = 0; i < 4; i++) {
        int c = c0 + ty + i * 8;
        oute[(size_t)c * R + r0 + tx] = f2bf(tile[tx][ty + i * 8]);
    }
}

// ------- router (fused x->bf16 convert): logits, losses (block-partial), top-2 -------
__global__ void router_kernel(const float* __restrict__ x, const float* __restrict__ rw,
                              unsigned short* __restrict__ xb,
                              int* __restrict__ top2, float2* __restrict__ loss_part) {
    int wave = threadIdx.x >> 6;
    int lane = threadIdx.x & 63;
    int t = blockIdx.x * 4 + wave;
    const float4* xr = (const float4*)(x + (size_t)t * H_DIM);
    float4 xv[4];
#pragma unroll
    for (int k = 0; k < 4; k++) xv[k] = xr[lane + 64 * k];
    uint2* xo = (uint2*)(xb + (size_t)t * H_DIM);
#pragma unroll
    for (int k = 0; k < 4; k++) {
        uint2 o;
        o.x = (uint32_t)f2bf(xv[k].x) | ((uint32_t)f2bf(xv[k].y) << 16);
        o.y = (uint32_t)f2bf(xv[k].z) | ((uint32_t)f2bf(xv[k].w) << 16);
        xo[lane + 64 * k] = o;
    }
    float acc[E_NUM];
#pragma unroll
    for (int e = 0; e < E_NUM; e++) {
        const float4* rr = (const float4*)(rw + e * H_DIM);
        float s = 0.f;
#pragma unroll
        for (int k = 0; k < 4; k++) {
            float4 r = rr[lane + 64 * k];
            s += xv[k].x * r.x + xv[k].y * r.y + xv[k].z * r.z + xv[k].w * r.w;
        }
        acc[e] = s;
    }
#pragma unroll
    for (int e = 0; e < E_NUM; e++) {
        float v = acc[e];
#pragma unroll
        for (int off = 32; off; off >>= 1) v += __shfl_xor(v, off);
        acc[e] = v;
    }
    __shared__ float red[8];
    if (lane == 0) {
        float mx = acc[0];
#pragma unroll
        for (int e = 1; e < E_NUM; e++) mx = fmaxf(mx, acc[e]);
        float s = 0.f;
#pragma unroll
        for (int e = 0; e < E_NUM; e++) s += expf(acc[e] - mx);
        float lse = mx + logf(s);
        float slogp = 0.f, ssq = 0.f;
#pragma unroll
        for (int e = 0; e < E_NUM; e++) { slogp += acc[e] - lse; ssq += acc[e] * acc[e]; }
        int i1 = 0; float m1 = acc[0];
#pragma unroll
        for (int e = 1; e < E_NUM; e++) if (acc[e] > m1) { m1 = acc[e]; i1 = e; }
        int i2 = -1; float m2 = -1e30f;
#pragma unroll
        for (int e = 0; e < E_NUM; e++) if (e != i1 && acc[e] > m2) { m2 = acc[e]; i2 = e; }
        top2[t] = i1 | (i2 << 8);
        red[wave] = slogp;
        red[4 + wave] = ssq;
    }
    __syncthreads();
    if (threadIdx.x == 0) {
        float2 p;
        p.x = red[0] + red[1] + red[2] + red[3];
        p.y = red[4] + red[5] + red[6] + red[7];
        loss_part[blockIdx.x] = p;
    }
}

// ---------------- histogram: per-block expert counts (LDS bins) ----------------
__global__ void hist_kernel(const int* __restrict__ top2, int* __restrict__ blockcounts) {
    __shared__ int cnt[E_NUM];
    if (threadIdx.x < E_NUM) cnt[threadIdx.x] = 0;
    __syncthreads();
    int t = blockIdx.x * 256 + threadIdx.x;
    int v = top2[t];
    atomicAdd(&cnt[v & 255], 1);
    atomicAdd(&cnt[v >> 8], 1);
    __syncthreads();
    if (threadIdx.x < E_NUM) blockcounts[blockIdx.x * E_NUM + threadIdx.x] = cnt[threadIdx.x];
}

// ---------------- scan + loss finalize (1 block) ----------------
__global__ void scan_kernel(const int* __restrict__ blockcounts, const float2* __restrict__ loss_part,
                            int* __restrict__ counts, int* __restrict__ basep, int* __restrict__ offs,
                            float* __restrict__ loss_out) {
    __shared__ float redx[4], redy[4];
    int tid = threadIdx.x;
    float sx = 0.f, sy = 0.f;
    for (int i = tid; i < T_TOK / 4; i += 256) {
        float2 p = loss_part[i];
        sx += p.x; sy += p.y;
    }
#pragma unroll
    for (int off = 32; off; off >>= 1) { sx += __shfl_xor(sx, off); sy += __shfl_xor(sy, off); }
    if ((tid & 63) == 0) { redx[tid >> 6] = sx; redy[tid >> 6] = sy; }
    __syncthreads();
    if (tid == 0) {
        float slogp = redx[0] + redx[1] + redx[2] + redx[3];
        float ssq = redy[0] + redy[1] + redy[2] + redy[3];
        float ideal = 1.0f / E_NUM;
        float aux = ideal * ((float)T_TOK * E_NUM * logf(ideal) - slogp) / BATCH * AUX_COEF;
        float z = ssq / ((float)T_TOK * E_NUM) * Z_COEF;
        loss_out[0] = aux + z;
    }
    if (tid < E_NUM) {
        int s = 0;
        for (int b = 0; b < NBLK_TOK; b++) s += blockcounts[b * E_NUM + tid];
        counts[tid] = s;
    }
    __syncthreads();
    if (tid == 0) {
        int s = 0;
        for (int e = 0; e < E_NUM; e++) { basep[e] = s; s += counts[e]; }
    }
    __syncthreads();
    if (tid < E_NUM) {
        int o = basep[tid];
        for (int b = 0; b < NBLK_TOK; b++) { offs[b * E_NUM + tid] = o; o += blockcounts[b * E_NUM + tid]; }
    }
}

// -------- scatter: LDS cursors + per-block offsets; record each token's 2 positions --------
__global__ void scatter_kernel(const int* __restrict__ top2, const int* __restrict__ offs,
                               int* __restrict__ rowlist, int* __restrict__ posv) {
    __shared__ int cur[E_NUM];
    if (threadIdx.x < E_NUM) cur[threadIdx.x] = 0;
    __syncthreads();
    int t = blockIdx.x * 256 + threadIdx.x;
    int v = top2[t];
    int e0 = v & 255, e1 = v >> 8;
    int r0 = atomicAdd(&cur[e0], 1);
    int r1 = atomicAdd(&cur[e1], 1);
    int p0 = offs[blockIdx.x * E_NUM + e0] + r0;
    int p1 = offs[blockIdx.x * E_NUM + e1] + r1;
    rowlist[p0] = t;
    rowlist[p1] = t;
    posv[t] = p0 | (p1 << 16);
}

// ---- combine: out[t] = ybuf[p0] + ybuf[p1] + b2[e0] + b2[e1] ----
__global__ void combine_kernel(const int* __restrict__ top2, const int* __restrict__ posv,
                               const unsigned short* __restrict__ ybuf, const float* __restrict__ b2,
                               float* __restrict__ out) {
    int t = blockIdx.x;
    int v = top2[t];
    int p = posv[t];
    int e0 = v & 255, e1 = v >> 8;
    int p0 = p & 0xffff, p1 = (p >> 16) & 0xffff;
    int i = threadIdx.x;  // 256 threads x 4 elems
    const ushort4* y0 = (const ushort4*)(ybuf + (size_t)p0 * H_DIM);
    const ushort4* y1 = (const ushort4*)(ybuf + (size_t)p1 * H_DIM);
    const float4* q0 = (const float4*)(b2 + (size_t)e0 * H_DIM);
    const float4* q1 = (const float4*)(b2 + (size_t)e1 * H_DIM);
    ushort4 a = y0[i], b = y1[i];
    float4 c0 = q0[i], c1 = q1[i];
    float4 o;
    o.x = bf2f(a.x) + bf2f(b.x) + c0.x + c1.x;
    o.y = bf2f(a.y) + bf2f(b.y) + c0.y + c1.y;
    o.z = bf2f(a.z) + bf2f(b.z) + c0.z + c1.z;
    o.w = bf2f(a.w) + bf2f(b.w) + c0.w + c1.w;
    ((float4*)(out + (size_t)t * H_DIM))[i] = o;
}

// =====================================================================================
// Grouped GEMM, 256x256, BK=64, 8 waves (2M x 4N), 8-phase READ-AHEAD schedule.
//
// LDS: 2 buffers x (A 32KB + B 32KB). Row = 128 B = 8 chunks of 16 B; chunk swizzle
// LDS[r][c] = global chunk c^(r&7) (verified 0 conflicts). Tile t reads buf t&1;
// stages during tile t fill tile t+2's regions in buf t&1 (already-consumed regions).
//
// Read-ahead: every ds_read is for a frag used ONE PHASE LATER, so its drain hides
// under the current MFMA cluster (this was the missing m201 mechanism; round-3's
// read-for-current-phase version serialized drain->MFMA and stuck at 25% MfmaUtil).
//   ph1(t): MFMA Q00(a03,b01_cur) | read b23(t+1)->nxt [4] | stage B-h0(t+2)
//   ph2(t): MFMA Q01(a03,b23_cur) | read a47(t)        [8] | stage B-h1(t+2)
//   ph3(t): MFMA Q10(a47,b01_cur) | read b01(t+1)->nxt [4] | stage A-h0(t+2) | vmcnt(6)
//   ph4(t): MFMA Q11(a47,b23_cur) | read a03(t+1)      [8] | stage A-h1(t+2) | vmcnt(4)
// b01/b23 live 5-7 phases -> two tile-parity register generations (cur/nxt swap).
// vmcnt ledger (in-order retire, 2 gl_lds per stage call):
//   end-ph3 vmcnt(6): retires A(t+1) (staged ph3/ph4(t-1)) before ph4 reads a03(t+1).
//   end-ph4 vmcnt(4): retires B(t+2) (staged ph1/ph2(t)) before ph1(t+1) reads b23(t+2).
// Per-phase trailing lgkmcnt(0): this phase's reads drain before any later stage
// overwrites their source region (WAR-safe by construction; reads had the whole MFMA
// cluster to complete, so it's ~free). Tail (t+2>=NKT): vmcnt(0), reads/stages skipped.
// Block mapping: bid&7 = expert -> XCD; expert weight panel stays L2-resident per XCD.
// =====================================================================================
template<int KD, int NTILES_N, bool IS_G1>
__global__ __launch_bounds__(512, 2)
void gemm8p(const unsigned short* __restrict__ A,    // xb [T,H] (G1) or h1 [2T,F] (G2)
            const unsigned short* __restrict__ Bt,   // w1t [E,F,H] or w2t [E,H,F]  (B^T)
            const float* __restrict__ bias_p,        // b1 [E,F] (G1) or unused
            const int* __restrict__ rowlist,
            const int* __restrict__ basep,
            const int* __restrict__ counts,
            unsigned short* __restrict__ Out)        // h1 [2T,F] or ybuf [2T,H]
{
    constexpr int ND = NTILES_N * GBN;
    constexpr int NKT = KD / GBK;
    static_assert(NKT >= 4 && (NKT & 1) == 0, "pipeline needs even NKT >= 4");

    int bid = blockIdx.x;
    int e = bid & 7;
    int q = bid >> 3;
    int nt = q % NTILES_N;
    int mt = q / NTILES_N;
    int n_e = counts[e];
    if (mt * GBM >= n_e) return;
    int base_e = basep[e];

    __shared__ __attribute__((aligned(16))) unsigned char lds[2][65536];

    int tid = threadIdx.x;
    int wv = tid >> 6, lane = tid & 63;

    // ---- staging sources: thread stages rows srow+{0,64,128,192}, swizzled chunk gc ----
    int srow = tid >> 3;                       // 0..63
    int gc = (tid & 7) ^ (srow & 7);           // global 16B chunk this thread fetches
    const unsigned short* aS[4];
    const unsigned short* bS[4];
#pragma unroll
    for (int i = 0; i < 4; i++) {
        int r = srow + i * 64;
        size_t ra;
        if (IS_G1) {
            int rr = min(mt * GBM + r, n_e - 1);
            ra = (size_t)rowlist[base_e + rr];
        } else {
            ra = (size_t)(base_e + min(mt * GBM + r, n_e - 1));
        }
        aS[i] = A + ra * KD + gc * 8;
        bS[i] = Bt + ((size_t)e * ND + nt * GBN + r) * KD + gc * 8;
    }

    auto stageA = [&](int buf, int h, int t) {   // A half h (rows h*128..h*128+127) of K-tile t
        char* d = (char*)lds + buf * 65536 + h * 16384 + wv * 1024;
        gl_lds16(aS[h * 2 + 0] + t * GBK, d);
        gl_lds16(aS[h * 2 + 1] + t * GBK, d + 8192);
    };
    auto stageB = [&](int buf, int h, int t) {
        char* d = (char*)lds + buf * 65536 + 32768 + h * 16384 + wv * 1024;
        gl_lds16(bS[h * 2 + 0] + t * GBK, d);
        gl_lds16(bS[h * 2 + 1] + t * GBK, d + 8192);
    };

    // ---- reader geometry ----
    int mlane = lane & 15, quad = lane >> 4;
    int wr = (wv >> 2) * 128;   // wave M base
    int wc = (wv & 3) * 64;     // wave N base
    int xk0 = (quad * 16) ^ ((mlane & 7) << 4);
    int xk1 = (64 + quad * 16) ^ ((mlane & 7) << 4);
    int aRow = (wr + mlane) * 128;            // + mi*2048 + xk[ks]
    int bRow = 32768 + (wc + mlane) * 128;    // + ni*2048 + xk[ks]

    f32x4 acc[8][4] = {};
    bf16x8 a03[4][2], a47[4][2];
    bf16x8 b01A[2][2], b01B[2][2], b23A[2][2], b23B[2][2];  // two tile-parity generations

    auto read_a = [&](const char* buf, int mbase, bf16x8 (&dst)[4][2]) {
#pragma unroll
        for (int mi = 0; mi < 4; mi++) {
            dst[mi][0] = *(const bf16x8*)(buf + aRow + (mbase + mi) * 2048 + xk0);
            dst[mi][1] = *(const bf16x8*)(buf + aRow + (mbase + mi) * 2048 + xk1);
        }
    };
    auto read_b = [&](const char* buf, int nbase, bf16x8 (&dst)[2][2]) {
#pragma unroll
        for (int ni = 0; ni < 2; ni++) {
            dst[ni][0] = *(const bf16x8*)(buf + bRow + (nbase + ni) * 2048 + xk0);
            dst[ni][1] = *(const bf16x8*)(buf + bRow + (nbase + ni) * 2048 + xk1);
        }
    };
    auto mfma_q = [&](int am, int bn, bf16x8 (&Af)[4][2], bf16x8 (&Bf)[2][2]) {
        __builtin_amdgcn_s_setprio(1);
#pragma unroll
        for (int ks = 0; ks < 2; ks++)
#pragma unroll
            for (int mi = 0; mi < 4; mi++)
#pragma unroll
                for (int ni = 0; ni < 2; ni++)
                    acc[am + mi][bn + ni] =
                        __builtin_amdgcn_mfma_f32_16x16x32_bf16(Af[mi][ks], Bf[ni][ks], acc[am + mi][bn + ni], 0, 0, 0);
        __builtin_amdgcn_s_setprio(0);
        __builtin_amdgcn_sched_barrier(0);
    };

    // ---- prologue: stage tiles 0 and 1 (B first, then A; order feeds the vmcnt ledger) ----
    stageB(0, 0, 0); stageB(0, 1, 0); stageA(0, 0, 0); stageA(0, 1, 0);
    stageB(1, 0, 1); stageB(1, 1, 1); stageA(1, 0, 1); stageA(1, 1, 1);
    asm volatile("s_waitcnt vmcnt(8)" ::: "memory");   // tile 0 fully resident
    __builtin_amdgcn_s_barrier();
    read_a((const char*)lds, 0, a03);
    read_b((const char*)lds, 0, b01A);
    read_b((const char*)lds, 2, b23A);
    asm volatile("s_waitcnt lgkmcnt(0)" ::: "memory");
    asm volatile("s_waitcnt vmcnt(4)" ::: "memory");   // B(1) resident (A(1) may remain in flight)
    __builtin_amdgcn_s_barrier();

    auto tile = [&](int t, int cbi,
                    bf16x8 (&b01_cur)[2][2], bf16x8 (&b01_nxt)[2][2],
                    bf16x8 (&b23_cur)[2][2], bf16x8 (&b23_nxt)[2][2]) {
        const char* Nb = (const char*)lds + (cbi ^ 1) * 65536;
        bool hv1 = (t + 1 < NKT), hv2 = (t + 2 < NKT);

        // ---- ph1: read b23(t+1); stage B-h0(t+2); MFMA Q00 ----
        if (hv1) read_b(Nb, 2, b23_nxt);
        if (hv2) stageB(cbi, 0, t + 2);
        __builtin_amdgcn_sched_barrier(0);
        __builtin_amdgcn_s_barrier();
        __builtin_amdgcn_sched_barrier(0);
        mfma_q(0, 0, a03, b01_cur);
        asm volatile("s_waitcnt lgkmcnt(0)" ::: "memory");
        __builtin_amdgcn_s_barrier();

        // ---- ph2: read a47(t); stage B-h1(t+2); MFMA Q01 ----
        read_a((const char*)lds + cbi * 65536, 4, a47);
        if (hv2) stageB(cbi, 1, t + 2);
        __builtin_amdgcn_sched_barrier(0);
        __builtin_amdgcn_s_barrier();
        __builtin_amdgcn_sched_barrier(0);
        mfma_q(0, 2, a03, b23_cur);
        asm volatile("s_waitcnt lgkmcnt(0)" ::: "memory");
        __builtin_amdgcn_s_barrier();

        // ---- ph3: read b01(t+1); stage A-h0(t+2); MFMA Q10; vmcnt(6) ----
        if (hv1) read_b(Nb, 0, b01_nxt);
        if (hv2) stageA(cbi, 0, t + 2);
        __builtin_amdgcn_sched_barrier(0);
        __builtin_amdgcn_s_barrier();
        __builtin_amdgcn_sched_barrier(0);
        mfma_q(4, 0, a47, b01_cur);
        asm volatile("s_waitcnt lgkmcnt(0)" ::: "memory");
        if (hv2) { asm volatile("s_waitcnt vmcnt(6)" ::: "memory"); }
        else     { asm volatile("s_waitcnt vmcnt(0)" ::: "memory"); }
        __builtin_amdgcn_s_barrier();

        // ---- ph4: read a03(t+1); stage A-h1(t+2); MFMA Q11; vmcnt(4) ----
        if (hv1) read_a(Nb, 0, a03);
        if (hv2) stageA(cbi, 1, t + 2);
        __builtin_amdgcn_sched_barrier(0);
        __builtin_amdgcn_s_barrier();
        __builtin_amdgcn_sched_barrier(0);
        mfma_q(4, 2, a47, b23_cur);
        asm volatile("s_waitcnt lgkmcnt(0)" ::: "memory");
        if (hv2) { asm volatile("s_waitcnt vmcnt(4)" ::: "memory"); }
        else     { asm volatile("s_waitcnt vmcnt(0)" ::: "memory"); }
        __builtin_amdgcn_s_barrier();
    };

    for (int tb = 0; tb < NKT; tb += 2) {
        tile(tb,     0, b01A, b01B, b23A, b23B);
        tile(tb + 1, 1, b01B, b01A, b23B, b23A);
    }

    // ---- epilogue ----
    float bias[4];
#pragma unroll
    for (int ni = 0; ni < 4; ni++) {
        if (IS_G1) bias[ni] = bias_p[(size_t)e * ND + nt * GBN + wc + ni * 16 + mlane];
        else bias[ni] = 0.f;
    }
#pragma unroll
    for (int mi = 0; mi < 8; mi++) {
        int mbase = mt * GBM + wr + mi * 16 + quad * 4;
#pragma unroll
        for (int r = 0; r < 4; r++) {
            int m = mbase + r;
            if (m < n_e) {
                unsigned short* orow = Out + (size_t)(base_e + m) * ND + nt * GBN + wc + mlane;
#pragma unroll
                for (int ni = 0; ni < 4; ni++) {
                    float c = acc[mi][ni][r] + bias[ni];
                    if (IS_G1) c = c / (1.f + __expf(-c));
                    orow[ni * 16] = f2bf(c);
                }
            }
        }
    }
}

extern "C" void kernel_launch(void* const* d_in, const int* in_sizes, int n_in,
                              void* d_out, int out_size, void* d_ws, size_t ws_size,
                              hipStream_t stream) {
    const float* x = (const float*)d_in[0];
    const float* rw = (const float*)d_in[1];
    const float* w1 = (const float*)d_in[2];
    const float* b1 = (const float*)d_in[3];
    const float* w2 = (const float*)d_in[4];
    const float* b2 = (const float*)d_in[5];
    float* out = (float*)d_out;

    char* ws = (char*)d_ws;
    int* counts      = (int*)(ws + 0);          // 8 ints
    int* basep       = (int*)(ws + 64);         // 8 ints
    int* blockcounts = (int*)(ws + 128);        // 32*8 ints
    int* offs        = (int*)(ws + 2048);       // 32*8 ints
    float2* loss_part = (float2*)(ws + 4096);   // 2048 float2
    int* top2        = (int*)(ws + 32768);      // 8192 ints
    int* rowlist     = (int*)(ws + 65536);      // 16384 ints = 64 KB
    int* posv        = (int*)(ws + 131072);     // 8192 ints = 32 KB
    unsigned short* xb  = (unsigned short*)(ws + 163840);
    unsigned short* w1t = (unsigned short*)(ws + 163840 + 16777216ULL);
    unsigned short* w2t = (unsigned short*)(ws + 163840 + 16777216ULL + 33554432ULL);
    unsigned short* h1  = (unsigned short*)(ws + 163840 + 16777216ULL + 2ULL * 33554432ULL);
    unsigned short* ybuf = w1t;  // w1t (32 MB) is dead after gemm1; reuse for y [2T,H] bf16

    transpose_conv_kernel<<<dim3(64, 32, 8), 256, 0, stream>>>(w1, w1t, H_DIM, F_DIM);
    transpose_conv_kernel<<<dim3(32, 64, 8), 256, 0, stream>>>(w2, w2t, F_DIM, H_DIM);
    router_kernel<<<T_TOK / 4, 256, 0, stream>>>(x, rw, xb, top2, loss_part);
    hist_kernel<<<NBLK_TOK, 256, 0, stream>>>(top2, blockcounts);
    scan_kernel<<<1, 256, 0, stream>>>(blockcounts, loss_part, counts, basep, offs,
                                       out + (size_t)T_TOK * H_DIM);
    scatter_kernel<<<NBLK_TOK, 256, 0, stream>>>(top2, offs, rowlist, posv);
    // G1: K=H_DIM(1024) -> NKT=16; N=F_DIM => 8 n-tiles
    gemm8p<H_DIM, F_DIM / GBN, true><<<8 * MT_CAP * (F_DIM / GBN), 512, 0, stream>>>(
        xb, w1t, b1, rowlist, basep, counts, h1);
    // G2: K=F_DIM(2048) -> NKT=32; N=H_DIM => 4 n-tiles
    gemm8p<F_DIM, H_DIM / GBN, false><<<8 * MT_CAP * (H_DIM / GBN), 512, 0, stream>>>(
        h1, w2t, nullptr, rowlist, basep, counts, ybuf);
    combine_kernel<<<T_TOK, 256, 0, stream>>>(top2, posv, ybuf, b2, out);
}

// Round 5
// 397.824 us; speedup vs baseline: 3.0772x; 3.0772x over previous
//
#include <hip/hip_runtime.h>
#include <stdint.h>

#define T_TOK 8192
#define H_DIM 1024
#define E_NUM 8
#define F_DIM 2048
#define BATCH 4
#define AUX_COEF 0.001f
#define Z_COEF 0.001f

#define NBLK_TOK 32       // blocks for hist/scatter (8192/256)

// ---- grouped GEMM params: 128x128 tile, 4 waves, 2 blocks/CU co-resident ----
#define GBM 128
#define GBN 128
#define GBK 64
#define MT_CAP 18         // 18*128 = 2304 rows capacity per expert (counts ~2048±55)

typedef __bf16 bf16x8 __attribute__((ext_vector_type(8)));
typedef float f32x4 __attribute__((ext_vector_type(4)));

__device__ __forceinline__ unsigned short f2bf(float f) {
    union { float f; uint32_t u; } v; v.f = f;
    uint32_t u = v.u;
    return (unsigned short)((u + 0x7FFFu + ((u >> 16) & 1u)) >> 16);
}
__device__ __forceinline__ float bf2f(unsigned short u) {
    union { uint32_t u; float f; } v; v.u = ((uint32_t)u) << 16; return v.f;
}

// async global->LDS, 16 B per lane; LDS dest = wave-uniform base + lane*16
__device__ __forceinline__ void gl_lds16(const void* g, void* l) {
    __builtin_amdgcn_global_load_lds((const __attribute__((address_space(1))) uint32_t*)g,
                                     (__attribute__((address_space(3))) uint32_t*)l, 16, 0, 0);
}

// ------------- transpose+convert: in [E,R,C] fp32 -> out [E,C,R] bf16 -------------
__global__ void transpose_conv_kernel(const float* __restrict__ in, unsigned short* __restrict__ out,
                                      int R, int C) {
    __shared__ float tile[32][33];
    int e = blockIdx.z;
    const float* ine = in + (size_t)e * R * C;
    unsigned short* oute = out + (size_t)e * R * C;
    int tx = threadIdx.x & 31, ty = threadIdx.x >> 5;  // 32x8
    int c0 = blockIdx.x * 32, r0 = blockIdx.y * 32;
#pragma unroll
    for (int i = 0; i < 4; i++) {
        int r = r0 + ty + i * 8;
        tile[ty + i * 8][tx] = ine[(size_t)r * C + c0 + tx];
    }
    __syncthreads();
#pragma unroll
    for (int i = 0; i < 4; i++) {
        int c = c0 + ty + i * 8;
        oute[(size_t)c * R + r0 + tx] = f2bf(tile[tx][ty + i * 8]);
    }
}

// ------- router (fused x->bf16 convert): logits, losses (block-partial), top-2 -------
__global__ void router_kernel(const float* __restrict__ x, const float* __restrict__ rw,
                              unsigned short* __restrict__ xb,
                              int* __restrict__ top2, float2* __restrict__ loss_part) {
    int wave = threadIdx.x >> 6;
    int lane = threadIdx.x & 63;
    int t = blockIdx.x * 4 + wave;
    const float4* xr = (const float4*)(x + (size_t)t * H_DIM);
    float4 xv[4];
#pragma unroll
    for (int k = 0; k < 4; k++) xv[k] = xr[lane + 64 * k];
    uint2* xo = (uint2*)(xb + (size_t)t * H_DIM);
#pragma unroll
    for (int k = 0; k < 4; k++) {
        uint2 o;
        o.x = (uint32_t)f2bf(xv[k].x) | ((uint32_t)f2bf(xv[k].y) << 16);
        o.y = (uint32_t)f2bf(xv[k].z) | ((uint32_t)f2bf(xv[k].w) << 16);
        xo[lane + 64 * k] = o;
    }
    float acc[E_NUM];
#pragma unroll
    for (int e = 0; e < E_NUM; e++) {
        const float4* rr = (const float4*)(rw + e * H_DIM);
        float s = 0.f;
#pragma unroll
        for (int k = 0; k < 4; k++) {
            float4 r = rr[lane + 64 * k];
            s += xv[k].x * r.x + xv[k].y * r.y + xv[k].z * r.z + xv[k].w * r.w;
        }
        acc[e] = s;
    }
#pragma unroll
    for (int e = 0; e < E_NUM; e++) {
        float v = acc[e];
#pragma unroll
        for (int off = 32; off; off >>= 1) v += __shfl_xor(v, off);
        acc[e] = v;
    }
    __shared__ float red[8];
    if (lane == 0) {
        float mx = acc[0];
#pragma unroll
        for (int e = 1; e < E_NUM; e++) mx = fmaxf(mx, acc[e]);
        float s = 0.f;
#pragma unroll
        for (int e = 0; e < E_NUM; e++) s += expf(acc[e] - mx);
        float lse = mx + logf(s);
        float slogp = 0.f, ssq = 0.f;
#pragma unroll
        for (int e = 0; e < E_NUM; e++) { slogp += acc[e] - lse; ssq += acc[e] * acc[e]; }
        int i1 = 0; float m1 = acc[0];
#pragma unroll
        for (int e = 1; e < E_NUM; e++) if (acc[e] > m1) { m1 = acc[e]; i1 = e; }
        int i2 = -1; float m2 = -1e30f;
#pragma unroll
        for (int e = 0; e < E_NUM; e++) if (e != i1 && acc[e] > m2) { m2 = acc[e]; i2 = e; }
        top2[t] = i1 | (i2 << 8);
        red[wave] = slogp;
        red[4 + wave] = ssq;
    }
    __syncthreads();
    if (threadIdx.x == 0) {
        float2 p;
        p.x = red[0] + red[1] + red[2] + red[3];
        p.y = red[4] + red[5] + red[6] + red[7];
        loss_part[blockIdx.x] = p;
    }
}

// ---------------- histogram: per-block expert counts (LDS bins) ----------------
__global__ void hist_kernel(const int* __restrict__ top2, int* __restrict__ blockcounts) {
    __shared__ int cnt[E_NUM];
    if (threadIdx.x < E_NUM) cnt[threadIdx.x] = 0;
    __syncthreads();
    int t = blockIdx.x * 256 + threadIdx.x;
    int v = top2[t];
    atomicAdd(&cnt[v & 255], 1);
    atomicAdd(&cnt[v >> 8], 1);
    __syncthreads();
    if (threadIdx.x < E_NUM) blockcounts[blockIdx.x * E_NUM + threadIdx.x] = cnt[threadIdx.x];
}

// ---------------- scan + loss finalize (1 block) ----------------
__global__ void scan_kernel(const int* __restrict__ blockcounts, const float2* __restrict__ loss_part,
                            int* __restrict__ counts, int* __restrict__ basep, int* __restrict__ offs,
                            float* __restrict__ loss_out) {
    __shared__ float redx[4], redy[4];
    int tid = threadIdx.x;
    float sx = 0.f, sy = 0.f;
    for (int i = tid; i < T_TOK / 4; i += 256) {
        float2 p = loss_part[i];
        sx += p.x; sy += p.y;
    }
#pragma unroll
    for (int off = 32; off; off >>= 1) { sx += __shfl_xor(sx, off); sy += __shfl_xor(sy, off); }
    if ((tid & 63) == 0) { redx[tid >> 6] = sx; redy[tid >> 6] = sy; }
    __syncthreads();
    if (tid == 0) {
        float slogp = redx[0] + redx[1] + redx[2] + redx[3];
        float ssq = redy[0] + redy[1] + redy[2] + redy[3];
        float ideal = 1.0f / E_NUM;
        float aux = ideal * ((float)T_TOK * E_NUM * logf(ideal) - slogp) / BATCH * AUX_COEF;
        float z = ssq / ((float)T_TOK * E_NUM) * Z_COEF;
        loss_out[0] = aux + z;
    }
    if (tid < E_NUM) {
        int s = 0;
        for (int b = 0; b < NBLK_TOK; b++) s += blockcounts[b * E_NUM + tid];
        counts[tid] = s;
    }
    __syncthreads();
    if (tid == 0) {
        int s = 0;
        for (int e = 0; e < E_NUM; e++) { basep[e] = s; s += counts[e]; }
    }
    __syncthreads();
    if (tid < E_NUM) {
        int o = basep[tid];
        for (int b = 0; b < NBLK_TOK; b++) { offs[b * E_NUM + tid] = o; o += blockcounts[b * E_NUM + tid]; }
    }
}

// -------- scatter: LDS cursors + per-block offsets; record each token's 2 positions --------
__global__ void scatter_kernel(const int* __restrict__ top2, const int* __restrict__ offs,
                               int* __restrict__ rowlist, int* __restrict__ posv) {
    __shared__ int cur[E_NUM];
    if (threadIdx.x < E_NUM) cur[threadIdx.x] = 0;
    __syncthreads();
    int t = blockIdx.x * 256 + threadIdx.x;
    int v = top2[t];
    int e0 = v & 255, e1 = v >> 8;
    int r0 = atomicAdd(&cur[e0], 1);
    int r1 = atomicAdd(&cur[e1], 1);
    int p0 = offs[blockIdx.x * E_NUM + e0] + r0;
    int p1 = offs[blockIdx.x * E_NUM + e1] + r1;
    rowlist[p0] = t;
    rowlist[p1] = t;
    posv[t] = p0 | (p1 << 16);
}

// ---- combine: out[t] = ybuf[p0] + ybuf[p1] + b2[e0] + b2[e1] ----
__global__ void combine_kernel(const int* __restrict__ top2, const int* __restrict__ posv,
                               const unsigned short* __restrict__ ybuf, const float* __restrict__ b2,
                               float* __restrict__ out) {
    int t = blockIdx.x;
    int v = top2[t];
    int p = posv[t];
    int e0 = v & 255, e1 = v >> 8;
    int p0 = p & 0xffff, p1 = (p >> 16) & 0xffff;
    int i = threadIdx.x;  // 256 threads x 4 elems
    const ushort4* y0 = (const ushort4*)(ybuf + (size_t)p0 * H_DIM);
    const ushort4* y1 = (const ushort4*)(ybuf + (size_t)p1 * H_DIM);
    const float4* q0 = (const float4*)(b2 + (size_t)e0 * H_DIM);
    const float4* q1 = (const float4*)(b2 + (size_t)e1 * H_DIM);
    ushort4 a = y0[i], b = y1[i];
    float4 c0 = q0[i], c1 = q1[i];
    float4 o;
    o.x = bf2f(a.x) + bf2f(b.x) + c0.x + c1.x;
    o.y = bf2f(a.y) + bf2f(b.y) + c0.y + c1.y;
    o.z = bf2f(a.z) + bf2f(b.z) + c0.z + c1.z;
    o.w = bf2f(a.w) + bf2f(b.w) + c0.w + c1.w;
    ((float4*)(out + (size_t)t * H_DIM))[i] = o;
}

// =====================================================================================
// Grouped GEMM, 128x128 tile, BK=64, 4 waves (2M x 2N of 64x64), 8-phase schedule.
// LDS: 2 buffers x (A 16KB + B 16KB) = 64 KB -> 2 blocks/CU co-resident (the round-5
// lever: tail quantization halves, and the two independent barrier groups overlap each
// other's stalls, m114). Schedule/swizzle identical to the verified round-3 skeleton;
// reads are for the CURRENT phase (round-4's read-ahead spilled to scratch — reverted).
//
// Row = 128 B = 8 chunks of 16 B; chunk swizzle LDS[r][c] = global chunk c^(r&7)
// (0 conflicts measured). Stager: thread tid -> row tid>>3 (+32*i), global chunk
// (tid&7)^(row&7); LDS dest linear. Reader byte = r*128 + ((ks*64+quad*16)^((mlane&7)<<4)).
//
// Per K-tile t (4 phases, each: reads+stage -> barrier -> lgkmcnt(0) -> 8 MFMA -> barrier):
//   ph1: read a01+b01 (8), stage B-h1(t+1), MFMA Q00
//   ph2: read b23    (4), stage A-h1(t+1), MFMA Q01
//   ph3: read a23    (4), stage B-h0(t+2), MFMA Q10
//   ph4: (0 reads),       stage A-h0(t+2), MFMA Q11, vmcnt(4) [tail: vmcnt(0)]
// vmcnt ledger (2 gl_lds per stage): end-ph4 outstanding=8; vmcnt(4) drains tile t+1's
// halves (staged ph1/ph2) before tile t+1 reads them; ph3/ph4's t+2 halves stay in flight.
// WAR: every region's reads drain at that phase's lgkmcnt(0), >=1 barrier before overwrite.
// Block mapping: bid&7 = expert -> XCD; expert weight panel stays L2-resident per XCD.
// =====================================================================================
template<int KD, int NTILES_N, bool IS_G1>
__global__ __launch_bounds__(256, 2)
void gemm8p(const unsigned short* __restrict__ A,    // xb [T,H] (G1) or h1 [2T,F] (G2)
            const unsigned short* __restrict__ Bt,   // w1t [E,F,H] or w2t [E,H,F]  (B^T)
            const float* __restrict__ bias_p,        // b1 [E,F] (G1) or unused
            const int* __restrict__ rowlist,
            const int* __restrict__ basep,
            const int* __restrict__ counts,
            unsigned short* __restrict__ Out)        // h1 [2T,F] or ybuf [2T,H]
{
    constexpr int ND = NTILES_N * GBN;
    constexpr int NKT = KD / GBK;
    static_assert(NKT >= 4, "pipeline needs >=4 K-tiles");

    int bid = blockIdx.x;
    int e = bid & 7;
    int q = bid >> 3;
    int nt = q % NTILES_N;
    int mt = q / NTILES_N;
    int n_e = counts[e];
    if (mt * GBM >= n_e) return;
    int base_e = basep[e];

    __shared__ __attribute__((aligned(16))) unsigned char lds[2][32768];

    int tid = threadIdx.x;
    int wv = tid >> 6, lane = tid & 63;

    // ---- staging sources: thread stages rows srow+{0,32,64,96}, swizzled chunk gc ----
    int srow = tid >> 3;                       // 0..31
    int gc = (tid & 7) ^ (srow & 7);           // global 16B chunk this thread fetches
    const unsigned short* aS[4];
    const unsigned short* bS[4];
#pragma unroll
    for (int i = 0; i < 4; i++) {
        int r = srow + i * 32;
        size_t ra;
        if (IS_G1) {
            int rr = min(mt * GBM + r, n_e - 1);
            ra = (size_t)rowlist[base_e + rr];
        } else {
            ra = (size_t)(base_e + min(mt * GBM + r, n_e - 1));
        }
        aS[i] = A + ra * KD + gc * 8;
        bS[i] = Bt + ((size_t)e * ND + nt * GBN + r) * KD + gc * 8;
    }

    auto stageA = [&](int buf, int h, int t) {   // A half h (rows h*64..h*64+63) of K-tile t
        char* d = (char*)lds + buf * 32768 + h * 8192 + wv * 1024;
        gl_lds16(aS[h * 2 + 0] + t * GBK, d);
        gl_lds16(aS[h * 2 + 1] + t * GBK, d + 4096);
    };
    auto stageB = [&](int buf, int h, int t) {
        char* d = (char*)lds + buf * 32768 + 16384 + h * 8192 + wv * 1024;
        gl_lds16(bS[h * 2 + 0] + t * GBK, d);
        gl_lds16(bS[h * 2 + 1] + t * GBK, d + 4096);
    };

    // ---- reader geometry ----
    int mlane = lane & 15, quad = lane >> 4;
    int wr = (wv >> 1) * 64;    // wave M base
    int wc = (wv & 1) * 64;     // wave N base
    int xk0 = (quad * 16) ^ ((mlane & 7) << 4);
    int xk1 = (64 + quad * 16) ^ ((mlane & 7) << 4);
    int aRow = (wr + mlane) * 128;            // + mi*2048 + xk[ks]
    int bRow = 16384 + (wc + mlane) * 128;    // + ni*2048 + xk[ks]

    f32x4 acc[4][4] = {};
    bf16x8 a01[2][2], a23[2][2], b01[2][2], b23[2][2];

    // ---- prologue: tile0 fully + tile1's B-h0, A-h0 ----
    stageA(0, 0, 0); stageA(0, 1, 0); stageB(0, 0, 0); stageB(0, 1, 0);
    stageB(1, 0, 1); stageA(1, 0, 1);
    asm volatile("s_waitcnt vmcnt(4)" ::: "memory");   // tile 0 fully resident
    __builtin_amdgcn_s_barrier();

    for (int t = 0; t < NKT; ++t) {
        const char* Ab = (const char*)lds + (t & 1) * 32768;
        int nb = (t + 1) & 1;

        // ---- ph1: read a01,b01; stage B-h1(t+1); MFMA Q00 ----
#pragma unroll
        for (int mi = 0; mi < 2; mi++) {
            a01[mi][0] = *(const bf16x8*)(Ab + aRow + mi * 2048 + xk0);
            a01[mi][1] = *(const bf16x8*)(Ab + aRow + mi * 2048 + xk1);
        }
#pragma unroll
        for (int ni = 0; ni < 2; ni++) {
            b01[ni][0] = *(const bf16x8*)(Ab + bRow + ni * 2048 + xk0);
            b01[ni][1] = *(const bf16x8*)(Ab + bRow + ni * 2048 + xk1);
        }
        if (t + 1 < NKT) stageB(nb, 1, t + 1);
        __builtin_amdgcn_s_barrier();
        asm volatile("s_waitcnt lgkmcnt(0)" ::: "memory");
        __builtin_amdgcn_sched_barrier(0);
        __builtin_amdgcn_s_setprio(1);
#pragma unroll
        for (int ks = 0; ks < 2; ks++)
#pragma unroll
            for (int mi = 0; mi < 2; mi++)
#pragma unroll
                for (int ni = 0; ni < 2; ni++)
                    acc[mi][ni] = __builtin_amdgcn_mfma_f32_16x16x32_bf16(a01[mi][ks], b01[ni][ks], acc[mi][ni], 0, 0, 0);
        __builtin_amdgcn_s_setprio(0);
        __builtin_amdgcn_s_barrier();

        // ---- ph2: read b23; stage A-h1(t+1); MFMA Q01 ----
#pragma unroll
        for (int ni = 0; ni < 2; ni++) {
            b23[ni][0] = *(const bf16x8*)(Ab + bRow + (ni + 2) * 2048 + xk0);
            b23[ni][1] = *(const bf16x8*)(Ab + bRow + (ni + 2) * 2048 + xk1);
        }
        if (t + 1 < NKT) stageA(nb, 1, t + 1);
        __builtin_amdgcn_s_barrier();
        asm volatile("s_waitcnt lgkmcnt(0)" ::: "memory");
        __builtin_amdgcn_sched_barrier(0);
        __builtin_amdgcn_s_setprio(1);
#pragma unroll
        for (int ks = 0; ks < 2; ks++)
#pragma unroll
            for (int mi = 0; mi < 2; mi++)
#pragma unroll
                for (int ni = 0; ni < 2; ni++)
                    acc[mi][ni + 2] = __builtin_amdgcn_mfma_f32_16x16x32_bf16(a01[mi][ks], b23[ni][ks], acc[mi][ni + 2], 0, 0, 0);
        __builtin_amdgcn_s_setprio(0);
        __builtin_amdgcn_s_barrier();

        // ---- ph3: read a23; stage B-h0(t+2); MFMA Q10 ----
#pragma unroll
        for (int mi = 0; mi < 2; mi++) {
            a23[mi][0] = *(const bf16x8*)(Ab + aRow + (mi + 2) * 2048 + xk0);
            a23[mi][1] = *(const bf16x8*)(Ab + aRow + (mi + 2) * 2048 + xk1);
        }
        if (t + 2 < NKT) stageB(t & 1, 0, t + 2);
        __builtin_amdgcn_s_barrier();
        asm volatile("s_waitcnt lgkmcnt(0)" ::: "memory");
        __builtin_amdgcn_sched_barrier(0);
        __builtin_amdgcn_s_setprio(1);
#pragma unroll
        for (int ks = 0; ks < 2; ks++)
#pragma unroll
            for (int mi = 0; mi < 2; mi++)
#pragma unroll
                for (int ni = 0; ni < 2; ni++)
                    acc[mi + 2][ni] = __builtin_amdgcn_mfma_f32_16x16x32_bf16(a23[mi][ks], b01[ni][ks], acc[mi + 2][ni], 0, 0, 0);
        __builtin_amdgcn_s_setprio(0);
        __builtin_amdgcn_s_barrier();

        // ---- ph4: stage A-h0(t+2); MFMA Q11; tile-boundary vmcnt ----
        if (t + 2 < NKT) stageA(t & 1, 0, t + 2);
        __builtin_amdgcn_s_barrier();
        __builtin_amdgcn_sched_barrier(0);
        __builtin_amdgcn_s_setprio(1);
#pragma unroll
        for (int ks = 0; ks < 2; ks++)
#pragma unroll
            for (int mi = 0; mi < 2; mi++)
#pragma unroll
                for (int ni = 0; ni < 2; ni++)
                    acc[mi + 2][ni + 2] = __builtin_amdgcn_mfma_f32_16x16x32_bf16(a23[mi][ks], b23[ni][ks], acc[mi + 2][ni + 2], 0, 0, 0);
        __builtin_amdgcn_s_setprio(0);
        if (t + 2 < NKT) {
            asm volatile("s_waitcnt vmcnt(4)" ::: "memory");   // ph3/ph4 stages may stay in flight
        } else {
            asm volatile("s_waitcnt vmcnt(0)" ::: "memory");   // tail: drain
        }
        __builtin_amdgcn_s_barrier();
    }

    // ---- epilogue ----
    float bias[4];
#pragma unroll
    for (int ni = 0; ni < 4; ni++) {
        if (IS_G1) bias[ni] = bias_p[(size_t)e * ND + nt * GBN + wc + ni * 16 + mlane];
        else bias[ni] = 0.f;
    }
#pragma unroll
    for (int mi = 0; mi < 4; mi++) {
        int mbase = mt * GBM + wr + mi * 16 + quad * 4;
#pragma unroll
        for (int r = 0; r < 4; r++) {
            int m = mbase + r;
            if (m < n_e) {
                unsigned short* orow = Out + (size_t)(base_e + m) * ND + nt * GBN + wc + mlane;
#pragma unroll
                for (int ni = 0; ni < 4; ni++) {
                    float c = acc[mi][ni][r] + bias[ni];
                    if (IS_G1) c = c / (1.f + __expf(-c));
                    orow[ni * 16] = f2bf(c);
                }
            }
        }
    }
}

extern "C" void kernel_launch(void* const* d_in, const int* in_sizes, int n_in,
                              void* d_out, int out_size, void* d_ws, size_t ws_size,
                              hipStream_t stream) {
    const float* x = (const float*)d_in[0];
    const float* rw = (const float*)d_in[1];
    const float* w1 = (const float*)d_in[2];
    const float* b1 = (const float*)d_in[3];
    const float* w2 = (const float*)d_in[4];
    const float* b2 = (const float*)d_in[5];
    float* out = (float*)d_out;

    char* ws = (char*)d_ws;
    int* counts      = (int*)(ws + 0);          // 8 ints
    int* basep       = (int*)(ws + 64);         // 8 ints
    int* blockcounts = (int*)(ws + 128);        // 32*8 ints
    int* offs        = (int*)(ws + 2048);       // 32*8 ints
    float2* loss_part = (float2*)(ws + 4096);   // 2048 float2
    int* top2        = (int*)(ws + 32768);      // 8192 ints
    int* rowlist     = (int*)(ws + 65536);      // 16384 ints = 64 KB
    int* posv        = (int*)(ws + 131072);     // 8192 ints = 32 KB
    unsigned short* xb  = (unsigned short*)(ws + 163840);
    unsigned short* w1t = (unsigned short*)(ws + 163840 + 16777216ULL);
    unsigned short* w2t = (unsigned short*)(ws + 163840 + 16777216ULL + 33554432ULL);
    unsigned short* h1  = (unsigned short*)(ws + 163840 + 16777216ULL + 2ULL * 33554432ULL);
    unsigned short* ybuf = w1t;  // w1t (32 MB) is dead after gemm1; reuse for y [2T,H] bf16

    transpose_conv_kernel<<<dim3(64, 32, 8), 256, 0, stream>>>(w1, w1t, H_DIM, F_DIM);
    transpose_conv_kernel<<<dim3(32, 64, 8), 256, 0, stream>>>(w2, w2t, F_DIM, H_DIM);
    router_kernel<<<T_TOK / 4, 256, 0, stream>>>(x, rw, xb, top2, loss_part);
    hist_kernel<<<NBLK_TOK, 256, 0, stream>>>(top2, blockcounts);
    scan_kernel<<<1, 256, 0, stream>>>(blockcounts, loss_part, counts, basep, offs,
                                       out + (size_t)T_TOK * H_DIM);
    scatter_kernel<<<NBLK_TOK, 256, 0, stream>>>(top2, offs, rowlist, posv);
    // G1: K=H_DIM(1024) -> NKT=16; N=F_DIM => 16 n-tiles; grid = 8*18*16 = 2304
    gemm8p<H_DIM, F_DIM / GBN, true><<<8 * MT_CAP * (F_DIM / GBN), 256, 0, stream>>>(
        xb, w1t, b1, rowlist, basep, counts, h1);
    // G2: K=F_DIM(2048) -> NKT=32; N=H_DIM => 8 n-tiles; grid = 8*18*8 = 1152
    gemm8p<F_DIM, H_DIM / GBN, false><<<8 * MT_CAP * (H_DIM / GBN), 256, 0, stream>>>(
        h1, w2t, nullptr, rowlist, basep, counts, ybuf);
    combine_kernel<<<T_TOK, 256, 0, stream>>>(top2, posv, ybuf, b2, out);
}